// Round 6
// baseline (555.813 us; speedup 1.0000x reference)
//
#include <hip/hip_runtime.h>
#include <float.h>
#include <stdint.h>

#define N_TOK 32768
#define N_E   8192
#define EDIM  256
#define MU_W  0.25f
#define NSPLIT 4
#define NRANGE 2048
#define BMr 128               /* block rows (tokens) */
#define BNr 256               /* block cols per tile */
#define NT8 8                 /* tiles per split: 2048/256 */
#define TQ  4                 /* K-chunks (64 each) per tile */
#define MARGIN_F 4096.0f      /* scaled units (2^25): 1.2e-4 d >= ref-ulp + 2*quantum + 8-sigma noise */
#define OFFSETF (-0x1p21f)    /* makes every score negative -> raw-bit u32 max-ordering */
#define XSCALE 512.0f         /* 2^9 */
#define ESCALE -131072.0f     /* -2^17 ; product sums to -dot*2^26 = -2dot*2^25 */

typedef _Float16 f16;
typedef _Float16 f16x8 __attribute__((ext_vector_type(8)));
typedef _Float16 f16x4 __attribute__((ext_vector_type(4)));
typedef float f32x4 __attribute__((ext_vector_type(4)));
typedef unsigned int u32;

// ws layout (bytes)
#define WS_EMB16   0
#define WS_SX      4194304
#define WS_SE      4325376
#define WS_SE25    4358144
#define WS_CAND    4390912
#define WS_PART    6488064
#define WS_RCNT    6619136
#define WS_RLIST   6619392

__device__ inline void gload_lds16(const void* g, void* l) {
  __builtin_amdgcn_global_load_lds(
      (const __attribute__((address_space(1))) unsigned int*)g,
      (__attribute__((address_space(3))) unsigned int*)l, 16, 0, 0);
}

__device__ inline u32 umax_(u32 a, u32 b) { return a > b ? a : b; }
__device__ inline u32 umin_(u32 a, u32 b) { return a < b ? a : b; }

__device__ inline u32 med3u(u32 a, u32 b, u32 c) {
  u32 r;
  asm("v_med3_u32 %0, %1, %2, %3" : "=v"(r) : "v"(a), "v"(b), "v"(c));
  return r;
}

// sorted top-4 insert, DESCENDING u32 (a>=b>=c>=d; larger u32 = more-negative float = better)
__device__ inline void ins4max(u32 v, u32& a, u32& b, u32& c, u32& d) {
  u32 na = umax_(a, v);
  u32 nb = med3u(a, b, v);
  u32 nc = med3u(b, c, v);
  u32 nd = med3u(c, d, v);
  a = na; b = nb; c = nc; d = nd;
}

__global__ void zero_kernel(u32* p) { p[0] = 0u; }

// ---------------- prepass: exact rownorm tree + (for emb) scaled/swizzled f16 + se*2^25 ----------------
__global__ __launch_bounds__(256) void conv_kernel(const float* __restrict__ src,
                                                   char* __restrict__ dst16,
                                                   float* __restrict__ norms,
                                                   float* __restrict__ norms25,
                                                   float scale, int write16, int nrows) {
  int wave = threadIdx.x >> 6;
  int lane = threadIdx.x & 63;
  int row = blockIdx.x * 4 + wave;
  if (row >= nrows) return;
  const float4 v = *(const float4*)(src + (size_t)row * EDIM + lane * 4);
  float s = (v.x * v.x + v.y * v.y) + (v.z * v.z + v.w * v.w);
#pragma unroll
  for (int off = 32; off >= 1; off >>= 1) s += __shfl_xor(s, off);
  if (lane == 0) {
    norms[row] = s;
    if (norms25) norms25[row] = s * 0x1p25f;   // exact pow2 scale of fl(se)
  }
  if (write16) {
    f16x4 h;
    h[0] = (f16)(v.x * scale); h[1] = (f16)(v.y * scale);
    h[2] = (f16)(v.z * scale); h[3] = (f16)(v.w * scale);
    int sw = (row & 7) << 4;
    *(f16x4*)(dst16 + (size_t)row * 512 + ((lane * 8) ^ sw)) = h;
  }
}

// ---------------- stage-1: fp16 MFMA GEMM, A resident in LDS, B double-buffered ----------------
// grid 1024: split = bid&3, bm = (bid>>2)*128. 512 threads = 8 waves (2 wm x 4 wn), wave-tile 64x64.
__global__ __launch_bounds__(512, 2) void vq_main(const float* __restrict__ x,
                                                  const char* __restrict__ e16,
                                                  const float* __restrict__ se25,
                                                  u32* __restrict__ cand) {
  __shared__ __align__(16) char Abuf[128 * 512];     // 64 KB: full-K swizzled A panel
  __shared__ __align__(16) char Bbuf[2][256 * 128];  // 2 x 32 KB: B K-chunk double buffer
  __shared__ u32 scratch[8][4][16][4];               // 8 KB inter-wave merge

  const int tid = threadIdx.x;          // 0..511
  const int lane = tid & 63;
  const int wid = tid >> 6;             // 0..7
  const int wm = wid >> 2;              // 0..1
  const int wn = wid & 3;               // 0..3
  const int l15 = lane & 15;
  const int lg  = lane >> 4;            // 0..3
  const int split = blockIdx.x & 3;
  const int bm = (blockIdx.x >> 2) * BMr;
  const int nbase = split * NRANGE;

  // ---- stage A ONCE: convert x rows (*2^9) to f16, XOR-swizzled rows of 512B ----
  {
    const int row = tid >> 2, seg = tid & 3;       // 128 rows x 4 segments of 64 floats
    const float4* xs = (const float4*)(x + (size_t)(bm + row) * EDIM + seg * 64);
    const int sw = (row & 7) << 4;
    char* ab = Abuf + row * 512;
#pragma unroll
    for (int u = 0; u < 8; ++u) {
      float4 a0 = xs[2 * u], a1 = xs[2 * u + 1];
      f16x8 hv;
      hv[0] = (f16)(a0.x * XSCALE); hv[1] = (f16)(a0.y * XSCALE);
      hv[2] = (f16)(a0.z * XSCALE); hv[3] = (f16)(a0.w * XSCALE);
      hv[4] = (f16)(a1.x * XSCALE); hv[5] = (f16)(a1.y * XSCALE);
      hv[6] = (f16)(a1.z * XSCALE); hv[7] = (f16)(a1.w * XSCALE);
      *(f16x8*)(ab + ((seg * 128 + u * 16) ^ sw)) = hv;
    }
  }
  // ---- stage B chunk (t=0,q=0) into Bbuf[0]: linear copy (e16 pre-swizzled) ----
  {
    const char* src = e16 + (size_t)nbase * 512;
#pragma unroll
    for (int j = 0; j < 4; ++j) {
      int tt = j * 512 + tid;
      gload_lds16(src + (size_t)(tt >> 3) * 512 + (tt & 7) * 16, Bbuf[0] + tt * 16);
    }
  }
  __syncthreads();   // drains vmcnt + lgkm, all waves see A and B(0,0)

  u32 d1[16], d2[16], d3[16], d4[16];
#pragma unroll
  for (int s = 0; s < 16; ++s) { d1[s] = 0u; d2[s] = 0u; d3[s] = 0u; d4[s] = 0u; }

  int cur = 0;
  for (int t = 0; t < NT8; ++t) {
    float sev[4];
#pragma unroll
    for (int ni = 0; ni < 4; ++ni)
      sev[ni] = se25[nbase + t * 256 + wn * 64 + ni * 16 + l15] + OFFSETF;

    f32x4 acc[4][4];
#pragma unroll
    for (int mi = 0; mi < 4; ++mi)
#pragma unroll
      for (int ni = 0; ni < 4; ++ni)
        acc[mi][ni] = (f32x4){sev[ni], sev[ni], sev[ni], sev[ni]};

    for (int q = 0; q < TQ; ++q) {
      const int step = t * TQ + q;
      // ---- issue next B-chunk stage into the other buffer (latency hides under MFMA) ----
      if (step + 1 < NT8 * TQ) {
        const int t2 = (step + 1) >> 2, q2 = (step + 1) & 3;
        const char* src = e16 + (size_t)(nbase + t2 * 256) * 512 + q2 * 128;
        char* dst = Bbuf[cur ^ 1];
#pragma unroll
        for (int j = 0; j < 4; ++j) {
          int tt = j * 512 + tid;
          gload_lds16(src + (size_t)(tt >> 3) * 512 + (tt & 7) * 16, dst + tt * 16);
        }
      }
      // ---- compute current chunk: 16 b128 frag reads + 32 MFMA ----
#pragma unroll
      for (int kk = 0; kk < 2; ++kk) {
        f16x8 av[4], bv[4];
#pragma unroll
        for (int mi = 0; mi < 4; ++mi) {
          const int ar = wm * 64 + mi * 16 + l15;
          av[mi] = *(const f16x8*)(Abuf + ar * 512 +
                                   ((q * 128 + kk * 64 + lg * 16) ^ ((ar & 7) << 4)));
        }
#pragma unroll
        for (int ni = 0; ni < 4; ++ni) {
          const int br = wn * 64 + ni * 16 + l15;
          bv[ni] = *(const f16x8*)(Bbuf[cur] + br * 128 +
                                   ((kk * 64 + lg * 16) ^ ((br & 7) << 4)));
        }
#pragma unroll
        for (int mi = 0; mi < 4; ++mi)
#pragma unroll
          for (int ni = 0; ni < 4; ++ni)
            acc[mi][ni] = __builtin_amdgcn_mfma_f32_16x16x32_f16(av[mi], bv[ni], acc[mi][ni], 0, 0, 0);
      }
      // ---- per-tile epilogue (before barrier: overlaps in-flight stage) ----
      if (q == TQ - 1) {
#pragma unroll
        for (int ni = 0; ni < 4; ++ni) {
          const u32 id = (u32)((t << 8) | (wn << 6) | (ni << 4) | l15);  // == split-local col
#pragma unroll
          for (int mi = 0; mi < 4; ++mi)
#pragma unroll
            for (int r = 0; r < 4; ++r) {
              u32 up = (__float_as_uint(acc[mi][ni][r]) & 0xFFFFF800u) | id;
              int s = mi * 4 + r;
              ins4max(up, d1[s], d2[s], d3[s], d4[s]);
            }
        }
      }
      __syncthreads();   // vmcnt(0)+lgkm drain + barrier: next buffer ready, cur free
      cur ^= 1;
    }
  }

  // ---- intra-wave 16-lane butterfly merge ----
#pragma unroll
  for (int off = 8; off >= 1; off >>= 1) {
#pragma unroll
    for (int s = 0; s < 16; ++s) {
      u32 e1 = (u32)__shfl_xor((int)d1[s], off);
      u32 e2 = (u32)__shfl_xor((int)d2[s], off);
      u32 e3 = (u32)__shfl_xor((int)d3[s], off);
      u32 e4 = (u32)__shfl_xor((int)d4[s], off);
      ins4max(e1, d1[s], d2[s], d3[s], d4[s]);
      ins4max(e2, d1[s], d2[s], d3[s], d4[s]);
      ins4max(e3, d1[s], d2[s], d3[s], d4[s]);
      ins4max(e4, d1[s], d2[s], d3[s], d4[s]);
    }
  }
  if (l15 == 0) {
#pragma unroll
    for (int s = 0; s < 16; ++s) {
      scratch[wid][lg][s][0] = d1[s];
      scratch[wid][lg][s][1] = d2[s];
      scratch[wid][lg][s][2] = d3[s];
      scratch[wid][lg][s][3] = d4[s];
    }
  }
  __syncthreads();
  // ---- cross-wave merge over the 4 wn waves; write per-split top-4 (best first) ----
  if (tid < 128) {
    const int row = tid;
    const int wmr = row >> 6, mi = (row >> 4) & 3, lgr = (row >> 2) & 3, rr = row & 3;
    const int s = mi * 4 + rr;
    u32 a1 = scratch[wmr * 4][lgr][s][0];
    u32 a2 = scratch[wmr * 4][lgr][s][1];
    u32 a3 = scratch[wmr * 4][lgr][s][2];
    u32 a4 = scratch[wmr * 4][lgr][s][3];
#pragma unroll
    for (int w = 1; w < 4; ++w) {
#pragma unroll
      for (int c = 0; c < 4; ++c)
        ins4max(scratch[wmr * 4 + w][lgr][s][c], a1, a2, a3, a4);
    }
    size_t base = (size_t)split * (N_TOK * 4) + (size_t)(bm + row) * 4;
    cand[base + 0] = a1; cand[base + 1] = a2; cand[base + 2] = a3; cand[base + 3] = a4;
  }
}

// ---------------- gather: float-margin select + guard + exact refine + output ----------------
__global__ __launch_bounds__(256) void vq_gather_kernel(
    const float* __restrict__ x, const float* __restrict__ emb,
    const float* __restrict__ sx, const float* __restrict__ se,
    const u32* __restrict__ cand,
    float* __restrict__ out_q, float* __restrict__ out_idx,
    float* __restrict__ partials,
    u32* __restrict__ rcnt, u32* __restrict__ rlist) {
  const int token = blockIdx.x;
  const int tid = threadIdx.x;
  __shared__ int s_j;
  __shared__ int s_cnt;
  __shared__ int s_cj[16];
  __shared__ float s_dv[16];
  __shared__ float red[4];

  if (tid == 0) {
    u32 u[16];
    float uf[16];
    float gmin = FLT_MAX;
#pragma unroll
    for (int sp = 0; sp < 4; ++sp)
#pragma unroll
      for (int c = 0; c < 4; ++c) {
        u32 v = cand[(size_t)sp * (N_TOK * 4) + (size_t)token * 4 + c];
        u[sp * 4 + c] = v;
        float f = __uint_as_float(v);   // all stored scores are negative floats
        uf[sp * 4 + c] = f;
        gmin = fminf(gmin, f);
      }
    // guard: if any split's 4th-best is within margin of global best, top-4
    // cannot prove containment -> exact full rescan of that token
    bool guard = false;
#pragma unroll
    for (int sp = 0; sp < 4; ++sp) guard = guard || (uf[sp * 4 + 3] <= gmin + MARGIN_F);
    int cnt;
    if (guard) {
      u32 slot = atomicAdd(rcnt, 1u);
      rlist[slot] = (u32)token;
      cnt = -1;
    } else {
      cnt = 0;
#pragma unroll
      for (int sp = 0; sp < 4; ++sp)
#pragma unroll
        for (int c = 0; c < 4; ++c) {
          int k = sp * 4 + c;
          if (uf[k] <= gmin + MARGIN_F)
            s_cj[cnt++] = sp * NRANGE + (int)(u[k] & 0x7FFu);   // id == split-local col
        }
      if (cnt == 1) s_j = s_cj[0];
    }
    s_cnt = cnt;
  }
  __syncthreads();
  int cnt = s_cnt;
  if (cnt < 0) return;   // uniform: token handled by rescan kernel
  if (cnt > 1 && tid < cnt) {
    int j = s_cj[tid];
    const float* xr = x + (size_t)token * EDIM;
    const float* er = emb + (size_t)j * EDIM;
    float a = 0.f;
    for (int k = 0; k < EDIM; ++k) a = fmaf(xr[k], er[k], a);   // exact reference chain
    s_dv[tid] = (sx[token] + se[j]) - 2.0f * a;                  // exact reference epilogue
  }
  __syncthreads();
  if (cnt > 1 && tid == 0) {
    float bd = s_dv[0]; int bj = s_cj[0];
    for (int c = 1; c < cnt; ++c) {
      float d = s_dv[c]; int j = s_cj[c];
      if (d < bd || (d == bd && j < bj)) { bd = d; bj = j; }
    }
    s_j = bj;
  }
  __syncthreads();
  const int j = s_j;
  if (tid == 0) out_idx[token] = (float)j;
  float xv = x[(size_t)token * EDIM + tid];
  float q  = emb[(size_t)j * EDIM + tid];
  float diff = q - xv;
  out_q[(size_t)token * EDIM + tid] = xv + diff;
  float sq = diff * diff;
#pragma unroll
  for (int off = 32; off >= 1; off >>= 1) sq += __shfl_xor(sq, off);
  const int wave = tid >> 6, lane = tid & 63;
  if (lane == 0) red[wave] = sq;
  __syncthreads();
  if (tid == 0) partials[token] = (red[0] + red[1]) + (red[2] + red[3]);
}

// ---------------- rescan: exact full argmin for guarded tokens ----------------
__global__ __launch_bounds__(256) void vq_rescan_kernel(
    const float* __restrict__ x, const float* __restrict__ emb,
    const float* __restrict__ sx, const float* __restrict__ se,
    const u32* __restrict__ rcnt, const u32* __restrict__ rlist,
    float* __restrict__ out_q, float* __restrict__ out_idx,
    float* __restrict__ partials) {
  const int tid = threadIdx.x;
  const int n = (int)rcnt[0];
  __shared__ float xs[EDIM];
  __shared__ float rd[4];
  __shared__ int   rj[4];
  __shared__ int   s_bj;

  for (int it = blockIdx.x; it < n; it += gridDim.x) {
    const int token = (int)rlist[it];
    xs[tid] = x[(size_t)token * EDIM + tid];
    __syncthreads();
    const float sxt = sx[token];
    float bd = FLT_MAX; int bj = 0;
    for (int c = 0; c < N_E / 256; ++c) {
      int j = tid * (N_E / 256) + c;
      const float* er = emb + (size_t)j * EDIM;
      float a = 0.f;
      for (int k = 0; k < EDIM; ++k) a = fmaf(xs[k], er[k], a);
      float d = (sxt + se[j]) - 2.0f * a;
      if (d < bd || (d == bd && j < bj)) { bd = d; bj = j; }
    }
    const int lane = tid & 63, wave = tid >> 6;
#pragma unroll
    for (int off = 32; off >= 1; off >>= 1) {
      float d2 = __shfl_xor(bd, off);
      int   j2 = __shfl_xor(bj, off);
      if (d2 < bd || (d2 == bd && j2 < bj)) { bd = d2; bj = j2; }
    }
    if (lane == 0) { rd[wave] = bd; rj[wave] = bj; }
    __syncthreads();
    if (tid == 0) {
      float bbd = rd[0]; int bbj = rj[0];
#pragma unroll
      for (int w = 1; w < 4; ++w) {
        if (rd[w] < bbd || (rd[w] == bbd && rj[w] < bbj)) { bbd = rd[w]; bbj = rj[w]; }
      }
      s_bj = bbj;
      out_idx[token] = (float)bbj;
    }
    __syncthreads();
    const int j = s_bj;
    float xv = xs[tid];
    float q  = emb[(size_t)j * EDIM + tid];
    float diff = q - xv;
    out_q[(size_t)token * EDIM + tid] = xv + diff;
    float sq = diff * diff;
#pragma unroll
    for (int off = 32; off >= 1; off >>= 1) sq += __shfl_xor(sq, off);
    if (lane == 0) rd[wave] = sq;
    __syncthreads();
    if (tid == 0) partials[token] = (rd[0] + rd[1]) + (rd[2] + rd[3]);
    __syncthreads();
  }
}

// ---------------- final loss reduction ----------------
__global__ __launch_bounds__(256) void vq_loss_kernel(const float* __restrict__ partials,
                                                      float* __restrict__ loss_out) {
  const int tid = threadIdx.x;
  float s = 0.f;
  for (int i = tid; i < N_TOK; i += 256) s += partials[i];
  __shared__ float red[4];
#pragma unroll
  for (int off = 32; off >= 1; off >>= 1) s += __shfl_xor(s, off);
  const int wave = tid >> 6, lane = tid & 63;
  if (lane == 0) red[wave] = s;
  __syncthreads();
  if (tid == 0) {
    float tot = (red[0] + red[1]) + (red[2] + red[3]);
    float mean = tot / (float)(N_TOK * EDIM);
    loss_out[0] = mean + MU_W * mean;
  }
}

extern "C" void kernel_launch(void* const* d_in, const int* in_sizes, int n_in,
                              void* d_out, int out_size, void* d_ws, size_t ws_size,
                              hipStream_t stream) {
  const float* x   = (const float*)d_in[0];
  const float* emb = (const float*)d_in[1];

  float* out      = (float*)d_out;
  float* out_q    = out;
  float* out_loss = out + (size_t)N_TOK * EDIM;
  float* out_idx  = out_loss + 1;

  char* w = (char*)d_ws;
  char*  emb16    = w + WS_EMB16;
  float* sx       = (float*)(w + WS_SX);
  float* se       = (float*)(w + WS_SE);
  float* se25     = (float*)(w + WS_SE25);
  u32*   cand     = (u32*)(w + WS_CAND);
  float* partials = (float*)(w + WS_PART);
  u32*   rcnt     = (u32*)(w + WS_RCNT);
  u32*   rlist    = (u32*)(w + WS_RLIST);

  zero_kernel<<<1, 1, 0, stream>>>(rcnt);
  conv_kernel<<<N_E / 4, 256, 0, stream>>>(emb, emb16, se, se25, ESCALE, 1, N_E);
  conv_kernel<<<N_TOK / 4, 256, 0, stream>>>(x, nullptr, sx, nullptr, XSCALE, 0, N_TOK);

  vq_main<<<NSPLIT * (N_TOK / BMr), 512, 0, stream>>>(x, emb16, se25, cand);

  vq_gather_kernel<<<N_TOK, 256, 0, stream>>>(x, emb, sx, se, cand, out_q, out_idx, partials,
                                              rcnt, rlist);
  vq_rescan_kernel<<<256, 256, 0, stream>>>(x, emb, sx, se, rcnt, rlist, out_q, out_idx, partials);
  vq_loss_kernel<<<1, 256, 0, stream>>>(partials, out_loss);
}

// Round 7
// 322.434 us; speedup vs baseline: 1.7238x; 1.7238x over previous
//
#include <hip/hip_runtime.h>
#include <float.h>
#include <stdint.h>

#define N_TOK 32768
#define N_E   8192
#define EDIM  256
#define MU_W  0.25f
#define NSPLIT 4
#define NRANGE 2048
#define BMr 128               /* block rows (tokens) */
#define BNr 256               /* block cols per tile */
#define NT8 8                 /* tiles per split: 2048/256 */
#define TQ  4                 /* K-chunks (64 each) per tile */
#define MARGIN_F 4096.0f      /* scaled units (2^25): 1.2e-4 d >= ref-ulp + 2*quantum + 8-sigma noise */
#define OFFSETF (-0x1p21f)    /* makes every score negative -> raw-bit u32 max-ordering */
#define XSCALE 512.0f         /* 2^9 */
#define ESCALE -131072.0f     /* -2^17 ; product sums to -dot*2^26 = -2dot*2^25 */

typedef _Float16 f16;
typedef _Float16 f16x8 __attribute__((ext_vector_type(8)));
typedef _Float16 f16x4 __attribute__((ext_vector_type(4)));
typedef float f32x4 __attribute__((ext_vector_type(4)));
typedef unsigned int u32;
typedef unsigned long long u64;

// ws layout (bytes)
#define WS_EMB16   0
#define WS_SX      4194304
#define WS_SE      4325376
#define WS_SE25    4358144
#define WS_CAND    4390912
#define WS_PART    6488064
#define WS_RCNT    6619136
#define WS_RLIST   6619392
#define WS_RBEST   6750464   /* 32768 x u64 */

__device__ inline void gload_lds16(const void* g, void* l) {
  __builtin_amdgcn_global_load_lds(
      (const __attribute__((address_space(1))) unsigned int*)g,
      (__attribute__((address_space(3))) unsigned int*)l, 16, 0, 0);
}

__device__ inline u32 umax_(u32 a, u32 b) { return a > b ? a : b; }
__device__ inline u32 umin_(u32 a, u32 b) { return a < b ? a : b; }

__device__ inline u32 med3u(u32 a, u32 b, u32 c) {
  u32 r;
  asm("v_med3_u32 %0, %1, %2, %3" : "=v"(r) : "v"(a), "v"(b), "v"(c));
  return r;
}

// sorted top-4 insert, DESCENDING u32 (a>=b>=c>=d; larger u32 = more-negative float = better)
__device__ inline void ins4max(u32 v, u32& a, u32& b, u32& c, u32& d) {
  u32 na = umax_(a, v);
  u32 nb = med3u(a, b, v);
  u32 nc = med3u(b, c, v);
  u32 nd = med3u(c, d, v);
  a = na; b = nb; c = nc; d = nd;
}

__global__ void zero_kernel(u32* p) { p[0] = 0u; }

// ---------------- prepass: exact rownorm tree + (for emb) scaled/swizzled f16 + se*2^25 ----------------
__global__ __launch_bounds__(256) void conv_kernel(const float* __restrict__ src,
                                                   char* __restrict__ dst16,
                                                   float* __restrict__ norms,
                                                   float* __restrict__ norms25,
                                                   float scale, int write16, int nrows) {
  int wave = threadIdx.x >> 6;
  int lane = threadIdx.x & 63;
  int row = blockIdx.x * 4 + wave;
  if (row >= nrows) return;
  const float4 v = *(const float4*)(src + (size_t)row * EDIM + lane * 4);
  float s = (v.x * v.x + v.y * v.y) + (v.z * v.z + v.w * v.w);
#pragma unroll
  for (int off = 32; off >= 1; off >>= 1) s += __shfl_xor(s, off);
  if (lane == 0) {
    norms[row] = s;
    if (norms25) norms25[row] = s * 0x1p25f;   // exact pow2 scale of fl(se)
  }
  if (write16) {
    f16x4 h;
    h[0] = (f16)(v.x * scale); h[1] = (f16)(v.y * scale);
    h[2] = (f16)(v.z * scale); h[3] = (f16)(v.w * scale);
    int sw = (row & 7) << 4;
    *(f16x4*)(dst16 + (size_t)row * 512 + ((lane * 8) ^ sw)) = h;
  }
}

// ---------------- stage-1: fp16 MFMA GEMM, A resident in LDS, B double-buffered ----------------
__global__ __launch_bounds__(512, 2) void vq_main(const float* __restrict__ x,
                                                  const char* __restrict__ e16,
                                                  const float* __restrict__ se25,
                                                  u32* __restrict__ cand) {
  __shared__ __align__(16) char Abuf[128 * 512];     // 64 KB: full-K swizzled A panel
  __shared__ __align__(16) char Bbuf[2][256 * 128];  // 2 x 32 KB: B K-chunk double buffer
  __shared__ u32 scratch[8][4][16][4];               // 8 KB inter-wave merge

  const int tid = threadIdx.x;          // 0..511
  const int lane = tid & 63;
  const int wid = tid >> 6;             // 0..7
  const int wm = wid >> 2;              // 0..1
  const int wn = wid & 3;               // 0..3
  const int l15 = lane & 15;
  const int lg  = lane >> 4;            // 0..3
  const int split = blockIdx.x & 3;
  const int bm = (blockIdx.x >> 2) * BMr;
  const int nbase = split * NRANGE;

  // ---- stage A ONCE: convert x rows (*2^9) to f16, XOR-swizzled rows of 512B ----
  {
    const int row = tid >> 2, seg = tid & 3;       // 128 rows x 4 segments of 64 floats
    const float4* xs = (const float4*)(x + (size_t)(bm + row) * EDIM + seg * 64);
    const int sw = (row & 7) << 4;
    char* ab = Abuf + row * 512;
#pragma unroll
    for (int u = 0; u < 8; ++u) {
      float4 a0 = xs[2 * u], a1 = xs[2 * u + 1];
      f16x8 hv;
      hv[0] = (f16)(a0.x * XSCALE); hv[1] = (f16)(a0.y * XSCALE);
      hv[2] = (f16)(a0.z * XSCALE); hv[3] = (f16)(a0.w * XSCALE);
      hv[4] = (f16)(a1.x * XSCALE); hv[5] = (f16)(a1.y * XSCALE);
      hv[6] = (f16)(a1.z * XSCALE); hv[7] = (f16)(a1.w * XSCALE);
      *(f16x8*)(ab + ((seg * 128 + u * 16) ^ sw)) = hv;
    }
  }
  // ---- stage B chunk (t=0,q=0) into Bbuf[0]: linear copy (e16 pre-swizzled) ----
  {
    const char* src = e16 + (size_t)nbase * 512;
#pragma unroll
    for (int j = 0; j < 4; ++j) {
      int tt = j * 512 + tid;
      gload_lds16(src + (size_t)(tt >> 3) * 512 + (tt & 7) * 16, Bbuf[0] + tt * 16);
    }
  }
  __syncthreads();   // drains vmcnt + lgkm, all waves see A and B(0,0)

  u32 d1[16], d2[16], d3[16], d4[16];
#pragma unroll
  for (int s = 0; s < 16; ++s) { d1[s] = 0u; d2[s] = 0u; d3[s] = 0u; d4[s] = 0u; }

  int cur = 0;
  for (int t = 0; t < NT8; ++t) {
    float sev[4];
#pragma unroll
    for (int ni = 0; ni < 4; ++ni)
      sev[ni] = se25[nbase + t * 256 + wn * 64 + ni * 16 + l15] + OFFSETF;

    f32x4 acc[4][4];
#pragma unroll
    for (int mi = 0; mi < 4; ++mi)
#pragma unroll
      for (int ni = 0; ni < 4; ++ni)
        acc[mi][ni] = (f32x4){sev[ni], sev[ni], sev[ni], sev[ni]};

    for (int q = 0; q < TQ; ++q) {
      const int step = t * TQ + q;
      // ---- issue next B-chunk stage into the other buffer (hides under MFMA) ----
      if (step + 1 < NT8 * TQ) {
        const int t2 = (step + 1) >> 2, q2 = (step + 1) & 3;
        const char* src = e16 + (size_t)(nbase + t2 * 256) * 512 + q2 * 128;
        char* dst = Bbuf[cur ^ 1];
#pragma unroll
        for (int j = 0; j < 4; ++j) {
          int tt = j * 512 + tid;
          gload_lds16(src + (size_t)(tt >> 3) * 512 + (tt & 7) * 16, dst + tt * 16);
        }
      }
      // ---- compute current chunk: 16 b128 frag reads + 32 MFMA ----
#pragma unroll
      for (int kk = 0; kk < 2; ++kk) {
        f16x8 av[4], bv[4];
#pragma unroll
        for (int mi = 0; mi < 4; ++mi) {
          const int ar = wm * 64 + mi * 16 + l15;
          av[mi] = *(const f16x8*)(Abuf + ar * 512 +
                                   ((q * 128 + kk * 64 + lg * 16) ^ ((ar & 7) << 4)));
        }
#pragma unroll
        for (int ni = 0; ni < 4; ++ni) {
          const int br = wn * 64 + ni * 16 + l15;
          bv[ni] = *(const f16x8*)(Bbuf[cur] + br * 128 +
                                   ((kk * 64 + lg * 16) ^ ((br & 7) << 4)));
        }
#pragma unroll
        for (int mi = 0; mi < 4; ++mi)
#pragma unroll
          for (int ni = 0; ni < 4; ++ni)
            acc[mi][ni] = __builtin_amdgcn_mfma_f32_16x16x32_f16(av[mi], bv[ni], acc[mi][ni], 0, 0, 0);
      }
      // ---- per-tile epilogue (before barrier: overlaps in-flight stage) ----
      if (q == TQ - 1) {
#pragma unroll
        for (int ni = 0; ni < 4; ++ni) {
          const u32 id = (u32)((t << 8) | (wn << 6) | (ni << 4) | l15);  // == split-local col
#pragma unroll
          for (int mi = 0; mi < 4; ++mi)
#pragma unroll
            for (int r = 0; r < 4; ++r) {
              u32 up = (__float_as_uint(acc[mi][ni][r]) & 0xFFFFF800u) | id;
              int s = mi * 4 + r;
              ins4max(up, d1[s], d2[s], d3[s], d4[s]);
            }
        }
      }
      __syncthreads();   // vmcnt(0)+lgkm drain + barrier: next buffer ready, cur free
      cur ^= 1;
    }
  }

  // ---- intra-wave 16-lane butterfly merge ----
#pragma unroll
  for (int off = 8; off >= 1; off >>= 1) {
#pragma unroll
    for (int s = 0; s < 16; ++s) {
      u32 e1 = (u32)__shfl_xor((int)d1[s], off);
      u32 e2 = (u32)__shfl_xor((int)d2[s], off);
      u32 e3 = (u32)__shfl_xor((int)d3[s], off);
      u32 e4 = (u32)__shfl_xor((int)d4[s], off);
      ins4max(e1, d1[s], d2[s], d3[s], d4[s]);
      ins4max(e2, d1[s], d2[s], d3[s], d4[s]);
      ins4max(e3, d1[s], d2[s], d3[s], d4[s]);
      ins4max(e4, d1[s], d2[s], d3[s], d4[s]);
    }
  }
  if (l15 == 0) {
#pragma unroll
    for (int s = 0; s < 16; ++s) {
      scratch[wid][lg][s][0] = d1[s];
      scratch[wid][lg][s][1] = d2[s];
      scratch[wid][lg][s][2] = d3[s];
      scratch[wid][lg][s][3] = d4[s];
    }
  }
  __syncthreads();
  // ---- cross-wave merge over the 4 wn waves; write per-split top-4 (best first) ----
  if (tid < 128) {
    const int row = tid;
    const int wmr = row >> 6, mi = (row >> 4) & 3, lgr = (row >> 2) & 3, rr = row & 3;
    const int s = mi * 4 + rr;
    u32 a1 = scratch[wmr * 4][lgr][s][0];
    u32 a2 = scratch[wmr * 4][lgr][s][1];
    u32 a3 = scratch[wmr * 4][lgr][s][2];
    u32 a4 = scratch[wmr * 4][lgr][s][3];
#pragma unroll
    for (int w = 1; w < 4; ++w) {
#pragma unroll
      for (int c = 0; c < 4; ++c)
        ins4max(scratch[wmr * 4 + w][lgr][s][c], a1, a2, a3, a4);
    }
    size_t base = (size_t)split * (N_TOK * 4) + (size_t)(bm + row) * 4;
    cand[base + 0] = a1; cand[base + 1] = a2; cand[base + 2] = a3; cand[base + 3] = a4;
  }
}

// ---------------- gather: float-margin select + guard + exact refine + output ----------------
__global__ __launch_bounds__(256) void vq_gather_kernel(
    const float* __restrict__ x, const float* __restrict__ emb,
    const float* __restrict__ sx, const float* __restrict__ se,
    const u32* __restrict__ cand,
    float* __restrict__ out_q, float* __restrict__ out_idx,
    float* __restrict__ partials,
    u32* __restrict__ rcnt, u32* __restrict__ rlist, u64* __restrict__ rbest) {
  const int token = blockIdx.x;
  const int tid = threadIdx.x;
  __shared__ int s_j;
  __shared__ int s_cnt;
  __shared__ int s_cj[16];
  __shared__ float s_dv[16];
  __shared__ float red[4];

  if (tid == 0) {
    u32 u[16];
    float uf[16];
    float gmin = FLT_MAX;
#pragma unroll
    for (int sp = 0; sp < 4; ++sp)
#pragma unroll
      for (int c = 0; c < 4; ++c) {
        u32 v = cand[(size_t)sp * (N_TOK * 4) + (size_t)token * 4 + c];
        u[sp * 4 + c] = v;
        float f = __uint_as_float(v);   // all stored scores are negative floats
        uf[sp * 4 + c] = f;
        gmin = fminf(gmin, f);
      }
    // guard: if any split's 4th-best is within margin of global best, top-4
    // cannot prove containment -> exact full rescan of that token
    bool guard = false;
#pragma unroll
    for (int sp = 0; sp < 4; ++sp) guard = guard || (uf[sp * 4 + 3] <= gmin + MARGIN_F);
    int cnt;
    if (guard) {
      u32 slot = atomicAdd(rcnt, 1u);
      rlist[slot] = (u32)token;
      rbest[slot] = ~0ull;
      cnt = -1;
    } else {
      cnt = 0;
#pragma unroll
      for (int sp = 0; sp < 4; ++sp)
#pragma unroll
        for (int c = 0; c < 4; ++c) {
          int k = sp * 4 + c;
          if (uf[k] <= gmin + MARGIN_F)
            s_cj[cnt++] = sp * NRANGE + (int)(u[k] & 0x7FFu);   // id == split-local col
        }
      if (cnt == 1) s_j = s_cj[0];
    }
    s_cnt = cnt;
  }
  __syncthreads();
  int cnt = s_cnt;
  if (cnt < 0) return;   // uniform: token handled by rescan kernels
  if (cnt > 1 && tid < cnt) {
    int j = s_cj[tid];
    const float* xr = x + (size_t)token * EDIM;
    const float* er = emb + (size_t)j * EDIM;
    float a = 0.f;
    for (int k = 0; k < EDIM; ++k) a = fmaf(xr[k], er[k], a);   // exact reference chain
    s_dv[tid] = (sx[token] + se[j]) - 2.0f * a;                  // exact reference epilogue
  }
  __syncthreads();
  if (cnt > 1 && tid == 0) {
    float bd = s_dv[0]; int bj = s_cj[0];
    for (int c = 1; c < cnt; ++c) {
      float d = s_dv[c]; int j = s_cj[c];
      if (d < bd || (d == bd && j < bj)) { bd = d; bj = j; }
    }
    s_j = bj;
  }
  __syncthreads();
  const int j = s_j;
  if (tid == 0) out_idx[token] = (float)j;
  float xv = x[(size_t)token * EDIM + tid];
  float q  = emb[(size_t)j * EDIM + tid];
  float diff = q - xv;
  out_q[(size_t)token * EDIM + tid] = xv + diff;
  float sq = diff * diff;
#pragma unroll
  for (int off = 32; off >= 1; off >>= 1) sq += __shfl_xor(sq, off);
  const int wave = tid >> 6, lane = tid & 63;
  if (lane == 0) red[wave] = sq;
  __syncthreads();
  if (tid == 0) partials[token] = (red[0] + red[1]) + (red[2] + red[3]);
}

// ---------------- rescan phase A: parallel exact scan, work-item = (token, 256-row chunk) ----------------
__global__ __launch_bounds__(256) void vq_rescan_scan(
    const float* __restrict__ x, const float* __restrict__ emb,
    const float* __restrict__ sx, const float* __restrict__ se,
    const u32* __restrict__ rcnt, const u32* __restrict__ rlist,
    u64* __restrict__ rbest) {
  const int tid = threadIdx.x;
  const int n = (int)rcnt[0];
  const int total = n * 32;          // 32 chunks x 256 rows = 8192 codes
  __shared__ float xs[EDIM];
  __shared__ u64 rw[4];

  for (int w = blockIdx.x; w < total; w += gridDim.x) {
    const int it = w >> 5, chunk = w & 31;
    const int token = (int)rlist[it];
    __syncthreads();                 // protect xs across grid-stride iterations
    xs[tid] = x[(size_t)token * EDIM + tid];
    __syncthreads();
    const float sxt = sx[token];
    const int j = chunk * 256 + tid;
    const float* er = emb + (size_t)j * EDIM;
    float a = 0.f;
#pragma unroll 8
    for (int k4 = 0; k4 < 64; ++k4) {   // float4 loads, sequential fmaf: exact reference order
      float4 e4 = ((const float4*)er)[k4];
      float4 x4 = ((const float4*)xs)[k4];
      a = fmaf(x4.x, e4.x, a);
      a = fmaf(x4.y, e4.y, a);
      a = fmaf(x4.z, e4.z, a);
      a = fmaf(x4.w, e4.w, a);
    }
    float d = (sxt + se[j]) - 2.0f * a;
    // d > 0 always (min ~240): raw fp32 bits are order-monotone; low word = j => lowest-j tie-break
    u64 pk = ((u64)__float_as_uint(d) << 32) | (u32)j;
    const int lane = tid & 63, wave = tid >> 6;
#pragma unroll
    for (int off = 32; off >= 1; off >>= 1) {
      u64 o = __shfl_xor(pk, off);
      pk = o < pk ? o : pk;
    }
    if (lane == 0) rw[wave] = pk;
    __syncthreads();
    if (tid == 0) {
      u64 b = rw[0];
#pragma unroll
      for (int ww = 1; ww < 4; ++ww) b = rw[ww] < b ? rw[ww] : b;
      atomicMin(rbest + it, b);
    }
  }
}

// ---------------- rescan phase B: write outputs for guarded tokens ----------------
__global__ __launch_bounds__(256) void vq_rescan_write(
    const float* __restrict__ x, const float* __restrict__ emb,
    const u32* __restrict__ rcnt, const u32* __restrict__ rlist,
    const u64* __restrict__ rbest,
    float* __restrict__ out_q, float* __restrict__ out_idx,
    float* __restrict__ partials) {
  const int tid = threadIdx.x;
  const int n = (int)rcnt[0];
  __shared__ float red[4];

  for (int it = blockIdx.x; it < n; it += gridDim.x) {
    const int token = (int)rlist[it];
    const int j = (int)(u32)(rbest[it] & 0xFFFFFFFFull);
    if (tid == 0) out_idx[token] = (float)j;
    float xv = x[(size_t)token * EDIM + tid];
    float q  = emb[(size_t)j * EDIM + tid];
    float diff = q - xv;
    out_q[(size_t)token * EDIM + tid] = xv + diff;
    float sq = diff * diff;
#pragma unroll
    for (int off = 32; off >= 1; off >>= 1) sq += __shfl_xor(sq, off);
    const int lane = tid & 63, wave = tid >> 6;
    __syncthreads();                 // protect red across grid-stride iterations
    if (lane == 0) red[wave] = sq;
    __syncthreads();
    if (tid == 0) partials[token] = (red[0] + red[1]) + (red[2] + red[3]);
  }
}

// ---------------- final loss reduction ----------------
__global__ __launch_bounds__(256) void vq_loss_kernel(const float* __restrict__ partials,
                                                      float* __restrict__ loss_out) {
  const int tid = threadIdx.x;
  float s = 0.f;
  for (int i = tid; i < N_TOK; i += 256) s += partials[i];
  __shared__ float red[4];
#pragma unroll
  for (int off = 32; off >= 1; off >>= 1) s += __shfl_xor(s, off);
  const int wave = tid >> 6, lane = tid & 63;
  if (lane == 0) red[wave] = s;
  __syncthreads();
  if (tid == 0) {
    float tot = (red[0] + red[1]) + (red[2] + red[3]);
    float mean = tot / (float)(N_TOK * EDIM);
    loss_out[0] = mean + MU_W * mean;
  }
}

extern "C" void kernel_launch(void* const* d_in, const int* in_sizes, int n_in,
                              void* d_out, int out_size, void* d_ws, size_t ws_size,
                              hipStream_t stream) {
  const float* x   = (const float*)d_in[0];
  const float* emb = (const float*)d_in[1];

  float* out      = (float*)d_out;
  float* out_q    = out;
  float* out_loss = out + (size_t)N_TOK * EDIM;
  float* out_idx  = out_loss + 1;

  char* w = (char*)d_ws;
  char*  emb16    = w + WS_EMB16;
  float* sx       = (float*)(w + WS_SX);
  float* se       = (float*)(w + WS_SE);
  float* se25     = (float*)(w + WS_SE25);
  u32*   cand     = (u32*)(w + WS_CAND);
  float* partials = (float*)(w + WS_PART);
  u32*   rcnt     = (u32*)(w + WS_RCNT);
  u32*   rlist    = (u32*)(w + WS_RLIST);
  u64*   rbest    = (u64*)(w + WS_RBEST);

  zero_kernel<<<1, 1, 0, stream>>>(rcnt);
  conv_kernel<<<N_E / 4, 256, 0, stream>>>(emb, emb16, se, se25, ESCALE, 1, N_E);
  conv_kernel<<<N_TOK / 4, 256, 0, stream>>>(x, nullptr, sx, nullptr, XSCALE, 0, N_TOK);

  vq_main<<<NSPLIT * (N_TOK / BMr), 512, 0, stream>>>(x, emb16, se25, cand);

  vq_gather_kernel<<<N_TOK, 256, 0, stream>>>(x, emb, sx, se, cand, out_q, out_idx, partials,
                                              rcnt, rlist, rbest);
  vq_rescan_scan<<<2048, 256, 0, stream>>>(x, emb, sx, se, rcnt, rlist, rbest);
  vq_rescan_write<<<64, 256, 0, stream>>>(x, emb, rcnt, rlist, rbest, out_q, out_idx, partials);
  vq_loss_kernel<<<1, 256, 0, stream>>>(partials, out_loss);
}